// Round 11
// baseline (58.851 us; speedup 1.0000x reference)
//
#include <hip/hip_runtime.h>
#include <float.h>

#define NPTS   8192
#define NB     4
#define BLK    256
#define NBDIR  (NB * 2)             // 8 (batch, direction) pairs
#define SSPLIT 4                    // source splits per bd
#define SRCPB  (NPTS / SSPLIT)      // 2048 sources per block
#define STAGE  1024                 // source points per LDS stage (32 KB)
#define NSTAGE (SRCPB / STAGE)      // 2
#define QPW    64                   // queries per wave (2 MFMA tiles of 32)
#define QPB    (4 * QPW)            // 256 queries per block
#define NQB    (NPTS / QPB)         // 32 query blocks per bd

typedef __attribute__((ext_vector_type(8)))  short          short8;
typedef __attribute__((ext_vector_type(8)))  unsigned short ushort8;
typedef __attribute__((ext_vector_type(16))) float          f32x16;

__device__ inline unsigned short f2bf(float x) {           // RNE f32 -> bf16
  unsigned u = __builtin_bit_cast(unsigned, x);
  u = u + 0x7FFFu + ((u >> 16) & 1u);
  return (unsigned short)(u >> 16);
}
__device__ inline float bf2f(unsigned short h) {
  unsigned u = ((unsigned)h) << 16;
  return __builtin_bit_cast(float, u);
}

// Pack per point, K=16 split over two 8-slot halves (see R6 notes):
// sum_k A[q][k]*B[s][k] = -2*(q.s) + |s|^2, every bf16 product exact in f32.
__global__ __launch_bounds__(BLK) void prep_kernel(
    const float* __restrict__ tpl, const float* __restrict__ src,
    ushort8* __restrict__ apack8, ushort8* __restrict__ bpack8) {
  int p = blockIdx.x * BLK + threadIdx.x;   // 0..65535 = cloud*8192 + i
  int cloud = p >> 13;                      // b*2 + (0=tpl,1=src)
  int i = p & (NPTS - 1);
  int b = cloud >> 1;
  const float* base = ((cloud & 1) ? src : tpl) + ((size_t)b * NPTS + i) * 3;
  float x = base[0], y = base[1], z = base[2];
  unsigned short hx = f2bf(x), hy = f2bf(y), hz = f2bf(z);
  float fx = bf2f(hx), fy = bf2f(hy), fz = bf2f(hz);
  unsigned short lx = f2bf(x - fx), ly = f2bf(y - fy), lz = f2bf(z - fz);
  float s2 = fmaf(x, x, fmaf(y, y, z * z));
  unsigned short s2h = f2bf(s2);
  unsigned short s2l = f2bf(s2 - bf2f(s2h));
  unsigned short nhx = f2bf(-2.0f * fx), nhy = f2bf(-2.0f * fy), nhz = f2bf(-2.0f * fz);
  unsigned short nlx = f2bf(-2.0f * bf2f(lx)), nly = f2bf(-2.0f * bf2f(ly)),
                 nlz = f2bf(-2.0f * bf2f(lz));
  const unsigned short ONE = 0x3F80;

  ushort8 arow = {hx, hy, hz, lx, ly, lz, ONE, 0};
  ushort8 blo  = {nhx, nhy, nhz, nhx, nhy, nhz, s2h, 0};
  ushort8 bhi  = {nlx, nly, nlz, nlx, nly, nlz, s2l, 0};
  apack8[p] = arow;                                      // [cloud][point]
  bpack8[((size_t)cloud * 2 + 0) * NPTS + i] = blo;      // [cloud][half][point]
  bpack8[((size_t)cloud * 2 + 1) * NPTS + i] = bhi;
}

// ---- REAL path: R6-exact structure (the best measured: 43.4 us total). ----
// Per iter: 1 ds_read_b128, 2 MFMA (d0,d1), 32 fminf.
__global__ __launch_bounds__(BLK) void chamfer_main_kernel(
    const ushort8* __restrict__ apack8, const ushort8* __restrict__ bpack8,
    float* __restrict__ cand) {
  __shared__ ushort8 blds8[2 * STAGE];    // 32 KB
  const int bd   = blockIdx.x & 7;
  const int rest = blockIdx.x >> 3;
  const int ss   = rest & (SSPLIT - 1);
  const int qblk = rest >> 2;
  const int t = threadIdx.x, w = t >> 6, l = t & 63;
  const int acloud = bd, bcloud = bd ^ 1;
  const int qbase = qblk * QPB + w * QPW;

  short8 a0 = __builtin_bit_cast(short8, apack8[(size_t)acloud * NPTS + qbase + (l & 31)]);
  short8 a1 = __builtin_bit_cast(short8, apack8[(size_t)acloud * NPTS + qbase + 32 + (l & 31)]);

  f32x16 m0, m1;
  #pragma unroll
  for (int j = 0; j < 16; ++j) { m0[j] = FLT_MAX; m1[j] = FLT_MAX; }
  const f32x16 zero = {0.f, 0.f, 0.f, 0.f, 0.f, 0.f, 0.f, 0.f,
                       0.f, 0.f, 0.f, 0.f, 0.f, 0.f, 0.f, 0.f};

  const size_t bbase = (size_t)bcloud * 2 * NPTS + (size_t)ss * SRCPB;

  for (int sg = 0; sg < NSTAGE; ++sg) {
    if (sg) __syncthreads();
    #pragma unroll
    for (int i = 0; i < STAGE / BLK; ++i) {
      int c = t + BLK * i;
      blds8[c]         = bpack8[bbase + sg * STAGE + c];
      blds8[STAGE + c] = bpack8[bbase + NPTS + sg * STAGE + c];
    }
    __syncthreads();

    const int rb = (l >> 5) * STAGE + (l & 31);
    #pragma unroll 4
    for (int st = 0; st < STAGE / 32; ++st) {
      short8 bf = __builtin_bit_cast(short8, blds8[rb + st * 32]);
      f32x16 d0 = __builtin_amdgcn_mfma_f32_32x32x16_bf16(a0, bf, zero, 0, 0, 0);
      #pragma unroll
      for (int j = 0; j < 16; ++j) m0[j] = fminf(m0[j], d0[j]);
      f32x16 d1 = __builtin_amdgcn_mfma_f32_32x32x16_bf16(a1, bf, zero, 0, 0, 0);
      #pragma unroll
      for (int j = 0; j < 16; ++j) m1[j] = fminf(m1[j], d1[j]);
    }
  }

  #pragma unroll
  for (int off = 1; off <= 16; off <<= 1) {
    #pragma unroll
    for (int j = 0; j < 16; ++j) {
      m0[j] = fminf(m0[j], __shfl_xor(m0[j], off, 64));
      m1[j] = fminf(m1[j], __shfl_xor(m1[j], off, 64));
    }
  }

  if ((l & 31) == 0) {
    const int radd = (l >> 5) * 4;
    float* cq = cand + ((size_t)(bd * SSPLIT + ss) * NPTS) + qbase;
    #pragma unroll
    for (int r = 0; r < 16; ++r) {
      int row = (r & 3) + 8 * (r >> 2) + radd;
      cq[row]      = m0[r];
      cq[32 + row] = m1[r];
    }
  }
}

// ---- ABLATION: identical loop, fmin consumption REMOVED. MFMA results kept
// live via element-read asm (rule 17: prevents DCE of the MFMA and ds_read).
// Its duration = dur_total - main-path total (subtraction readout).
__global__ __launch_bounds__(BLK) void ablate_nomin_kernel(
    const ushort8* __restrict__ apack8, const ushort8* __restrict__ bpack8,
    float* __restrict__ dump) {
  __shared__ ushort8 blds8[2 * STAGE];
  const int bd   = blockIdx.x & 7;
  const int rest = blockIdx.x >> 3;
  const int ss   = rest & (SSPLIT - 1);
  const int qblk = rest >> 2;
  const int t = threadIdx.x, w = t >> 6, l = t & 63;
  const int acloud = bd, bcloud = bd ^ 1;
  const int qbase = qblk * QPB + w * QPW;

  short8 a0 = __builtin_bit_cast(short8, apack8[(size_t)acloud * NPTS + qbase + (l & 31)]);
  short8 a1 = __builtin_bit_cast(short8, apack8[(size_t)acloud * NPTS + qbase + 32 + (l & 31)]);

  f32x16 m0, m1;
  #pragma unroll
  for (int j = 0; j < 16; ++j) { m0[j] = FLT_MAX; m1[j] = FLT_MAX; }
  const f32x16 zero = {0.f, 0.f, 0.f, 0.f, 0.f, 0.f, 0.f, 0.f,
                       0.f, 0.f, 0.f, 0.f, 0.f, 0.f, 0.f, 0.f};

  const size_t bbase = (size_t)bcloud * 2 * NPTS + (size_t)ss * SRCPB;

  for (int sg = 0; sg < NSTAGE; ++sg) {
    if (sg) __syncthreads();
    #pragma unroll
    for (int i = 0; i < STAGE / BLK; ++i) {
      int c = t + BLK * i;
      blds8[c]         = bpack8[bbase + sg * STAGE + c];
      blds8[STAGE + c] = bpack8[bbase + NPTS + sg * STAGE + c];
    }
    __syncthreads();

    const int rb = (l >> 5) * STAGE + (l & 31);
    #pragma unroll 4
    for (int st = 0; st < STAGE / 32; ++st) {
      short8 bf = __builtin_bit_cast(short8, blds8[rb + st * 32]);
      f32x16 d0 = __builtin_amdgcn_mfma_f32_32x32x16_bf16(a0, bf, zero, 0, 0, 0);
      asm volatile("" :: "v"(d0[0]), "v"(d0[15]));   // keep MFMA live, no min
      f32x16 d1 = __builtin_amdgcn_mfma_f32_32x32x16_bf16(a1, bf, zero, 0, 0, 0);
      asm volatile("" :: "v"(d1[0]), "v"(d1[15]));
    }
  }

  // Same epilogue shape (m stays FLT_MAX); writes garbage to dump slice.
  #pragma unroll
  for (int off = 1; off <= 16; off <<= 1) {
    #pragma unroll
    for (int j = 0; j < 16; ++j) {
      m0[j] = fminf(m0[j], __shfl_xor(m0[j], off, 64));
      m1[j] = fminf(m1[j], __shfl_xor(m1[j], off, 64));
    }
  }
  if ((l & 31) == 0) {
    const int radd = (l >> 5) * 4;
    float* cq = dump + ((size_t)(bd * SSPLIT + ss) * NPTS) + qbase;
    #pragma unroll
    for (int r = 0; r < 16; ++r) {
      int row = (r & 3) + 8 * (r >> 2) + radd;
      cq[row]      = m0[r];
      cq[32 + row] = m1[r];
    }
  }
}

// Combine: per query, min over SSPLIT partials + |q|^2, block-sum.
__global__ __launch_bounds__(BLK) void combine_kernel(
    const float* __restrict__ tpl, const float* __restrict__ src,
    const float* __restrict__ cand, float* __restrict__ partial) {
  __shared__ float wsum[BLK / 64];
  const int qblk = blockIdx.x & 31;
  const int bd   = blockIdx.x >> 5;
  const int b = bd >> 1, dir = bd & 1;
  const int t = threadIdx.x;
  const int q = qblk * BLK + t;
  const float* base = cand + (size_t)bd * SSPLIT * NPTS + q;
  float v = fminf(fminf(base[0 * NPTS], base[1 * NPTS]),
                  fminf(base[2 * NPTS], base[3 * NPTS]));
  const float* qp = (dir ? src : tpl) + ((size_t)b * NPTS + q) * 3;
  v += fmaf(qp[0], qp[0], fmaf(qp[1], qp[1], qp[2] * qp[2]));
  #pragma unroll
  for (int off = 32; off > 0; off >>= 1) v += __shfl_down(v, off, 64);
  if ((t & 63) == 0) wsum[t >> 6] = v;
  __syncthreads();
  if (t == 0)
    partial[blockIdx.x] = wsum[0] + wsum[1] + wsum[2] + wsum[3];
}

// Final: fixed-order sum of 256 partials; mean over 2*B*N = 32768 mins.
__global__ __launch_bounds__(BLK) void final256_kernel(
    const float* __restrict__ partial, float* __restrict__ out) {
  __shared__ float wsum[BLK / 64];
  int t = threadIdx.x;
  float v = partial[t];
  #pragma unroll
  for (int off = 32; off > 0; off >>= 1) v += __shfl_down(v, off, 64);
  if ((t & 63) == 0) wsum[t >> 6] = v;
  __syncthreads();
  if (t == 0)
    out[0] = (wsum[0] + wsum[1] + wsum[2] + wsum[3]) * (1.0f / 32768.0f);
}

// ---------------- fallback (R2-style) if ws is too small --------------------
#define TILE   2048
#define NTILES (NPTS / TILE)
#define QBLKS  (NPTS / BLK)

__global__ __launch_bounds__(BLK) void chamfer_min_kernel(
    const float* __restrict__ tpl, const float* __restrict__ src,
    float* __restrict__ partial) {
  __shared__ float4 s4[TILE];
  __shared__ float wsum[BLK / 64];
  const int b = blockIdx.z, dir = blockIdx.y;
  const float* qb = (dir == 0 ? tpl : src) + (size_t)b * NPTS * 3;
  const float* rb = (dir == 0 ? src : tpl) + (size_t)b * NPTS * 3;
  const int t = threadIdx.x;
  const int q = blockIdx.x * BLK + t;
  const float qx = qb[3 * q + 0], qy = qb[3 * q + 1], qz = qb[3 * q + 2];
  const float q2 = fmaf(qx, qx, fmaf(qy, qy, qz * qz));
  float b0 = FLT_MAX, b1 = FLT_MAX;
  for (int tile = 0; tile < NTILES; ++tile) {
    const float* rt = rb + 3 * TILE * tile;
    #pragma unroll
    for (int k = 0; k < TILE / BLK; ++k) {
      int p = t + BLK * k;
      float x = rt[3 * p + 0], y = rt[3 * p + 1], z = rt[3 * p + 2];
      s4[p] = make_float4(-2.0f * x, -2.0f * y, -2.0f * z,
                          fmaf(x, x, fmaf(y, y, z * z)));
    }
    __syncthreads();
    #pragma unroll 2
    for (int m = 0; m < TILE; m += 2) {
      float4 p0 = s4[m + 0], p1 = s4[m + 1];
      float d0 = fmaf(qx, p0.x, fmaf(qy, p0.y, fmaf(qz, p0.z, p0.w)));
      float d1 = fmaf(qx, p1.x, fmaf(qy, p1.y, fmaf(qz, p1.z, p1.w)));
      b0 = fminf(b0, fminf(d0, d1));
      b1 = fminf(b1, d0);
    }
    __syncthreads();
  }
  float best = fminf(b0, b1) + q2;
  float v = best;
  #pragma unroll
  for (int off = 32; off > 0; off >>= 1) v += __shfl_down(v, off, 64);
  if ((t & 63) == 0) wsum[t >> 6] = v;
  __syncthreads();
  if (t == 0)
    partial[((b * 2 + dir) * QBLKS) + blockIdx.x] =
        wsum[0] + wsum[1] + wsum[2] + wsum[3];
}

// ----------------------------------------------------------------------------
extern "C" void kernel_launch(void* const* d_in, const int* in_sizes, int n_in,
                              void* d_out, int out_size, void* d_ws, size_t ws_size,
                              hipStream_t stream) {
  const float* tpl = (const float*)d_in[0];   // template (4, 8192, 3) f32
  const float* src = (const float*)d_in[1];   // source   (4, 8192, 3) f32
  float* out = (float*)d_out;

  const size_t a_chunks = (size_t)NBDIR * NPTS;            // 64 K ushort8 (1 MB)
  const size_t b_chunks = (size_t)NBDIR * 2 * NPTS;        // 128 K ushort8 (2 MB)
  const size_t cand_elems = (size_t)NBDIR * SSPLIT * NPTS; // 256 K f32 (1 MB)
  const size_t need = (a_chunks + b_chunks) * 16 +
                      (2 * cand_elems + NBDIR * NQB) * sizeof(float);

  if (ws_size >= need) {
    ushort8* apack8 = (ushort8*)d_ws;
    ushort8* bpack8 = apack8 + a_chunks;
    float*   cand   = (float*)(bpack8 + b_chunks);
    float*   dump   = cand + cand_elems;
    float*   partial = dump + cand_elems;
    prep_kernel<<<(NBDIR * NPTS) / BLK, BLK, 0, stream>>>(tpl, src, apack8, bpack8);
    chamfer_main_kernel<<<NBDIR * SSPLIT * NQB, BLK, 0, stream>>>(apack8, bpack8, cand);
    ablate_nomin_kernel<<<NBDIR * SSPLIT * NQB, BLK, 0, stream>>>(apack8, bpack8, dump);
    combine_kernel<<<NBDIR * QBLKS, BLK, 0, stream>>>(tpl, src, cand, partial);
    final256_kernel<<<1, BLK, 0, stream>>>(partial, out);
  } else {
    float* partial = (float*)d_ws;            // 256 floats
    dim3 grid(QBLKS, 2, NB);
    chamfer_min_kernel<<<grid, BLK, 0, stream>>>(tpl, src, partial);
    final256_kernel<<<1, BLK, 0, stream>>>(partial, out);
  }
}

// Round 12
// 45.650 us; speedup vs baseline: 1.2892x; 1.2892x over previous
//
#include <hip/hip_runtime.h>
#include <float.h>

#define NPTS   8192
#define NB     4
#define BLK    256
#define NBDIR  (NB * 2)             // 8 (batch, direction) pairs
#define SSPLIT 8                    // source splits per bd
#define SRCPB  (NPTS / SSPLIT)      // 1024 sources per block
#define STAGE  512                  // source points per LDS stage (16 KB)
#define NSTAGE (SRCPB / STAGE)      // 2
#define QPW    64                   // queries per wave (2 MFMA tiles of 32)
#define QPB    (4 * QPW)            // 256 queries per block
#define NQB    (NPTS / QPB)         // 32 query blocks per bd

typedef __attribute__((ext_vector_type(8)))  short          short8;
typedef __attribute__((ext_vector_type(8)))  unsigned short ushort8;
typedef __attribute__((ext_vector_type(16))) float          f32x16;

__device__ inline unsigned short f2bf(float x) {           // RNE f32 -> bf16
  unsigned u = __builtin_bit_cast(unsigned, x);
  u = u + 0x7FFFu + ((u >> 16) & 1u);
  return (unsigned short)(u >> 16);
}
__device__ inline float bf2f(unsigned short h) {
  unsigned u = ((unsigned)h) << 16;
  return __builtin_bit_cast(float, u);
}

// Pack per point, K=16 split over two 8-slot halves:
//   A row (both halves identical): [hx,hy,hz,lx,ly,lz,1,0]
//   B lo half: [-2hx,-2hy,-2hz,-2hx,-2hy,-2hz,s2h,0]
//   B hi half: [-2lx,-2ly,-2lz,-2lx,-2ly,-2lz,s2l,0]
// sum_k A[q][k]*B[s][k] = -2*(q.s) + |s|^2, every bf16 product exact in f32.
__global__ __launch_bounds__(BLK) void prep_kernel(
    const float* __restrict__ tpl, const float* __restrict__ src,
    ushort8* __restrict__ apack8, ushort8* __restrict__ bpack8) {
  int p = blockIdx.x * BLK + threadIdx.x;   // 0..65535 = cloud*8192 + i
  int cloud = p >> 13;                      // b*2 + (0=tpl,1=src)
  int i = p & (NPTS - 1);
  int b = cloud >> 1;
  const float* base = ((cloud & 1) ? src : tpl) + ((size_t)b * NPTS + i) * 3;
  float x = base[0], y = base[1], z = base[2];
  unsigned short hx = f2bf(x), hy = f2bf(y), hz = f2bf(z);
  float fx = bf2f(hx), fy = bf2f(hy), fz = bf2f(hz);
  unsigned short lx = f2bf(x - fx), ly = f2bf(y - fy), lz = f2bf(z - fz);
  float s2 = fmaf(x, x, fmaf(y, y, z * z));
  unsigned short s2h = f2bf(s2);
  unsigned short s2l = f2bf(s2 - bf2f(s2h));
  unsigned short nhx = f2bf(-2.0f * fx), nhy = f2bf(-2.0f * fy), nhz = f2bf(-2.0f * fz);
  unsigned short nlx = f2bf(-2.0f * bf2f(lx)), nly = f2bf(-2.0f * bf2f(ly)),
                 nlz = f2bf(-2.0f * bf2f(lz));
  const unsigned short ONE = 0x3F80;

  ushort8 arow = {hx, hy, hz, lx, ly, lz, ONE, 0};
  ushort8 blo  = {nhx, nhy, nhz, nhx, nhy, nhz, s2h, 0};
  ushort8 bhi  = {nlx, nly, nlz, nlx, nly, nlz, s2l, 0};
  apack8[p] = arow;                                      // [cloud][point]
  bpack8[((size_t)cloud * 2 + 0) * NPTS + i] = blo;      // [cloud][half][point]
  bpack8[((size_t)cloud * 2 + 1) * NPTS + i] = bhi;
}

// Main: R6-exact consumption (fminf(m, d): ONE MFMA-result operand per VALU
// op -> no accvgpr shuttle; min3 variants with two d-operands all regressed),
// at 2x the occupancy: 16 KB LDS + 2048 blocks = 8 blocks/CU, 32 waves/CU,
// to hide the MFMA->fmin dependency stall that the R11 ablation isolated
// (consumption = 22 us of main's 37 us at 4 waves/SIMD).
// Fragment maps: A row=l&31, B col=l&31 (k-half via l>>5, order-invariant
// because A's two k-halves are identical); C/D (verified m74/m101):
// col=l&31, row=(reg&3)+8*(reg>>2)+4*(l>>5).
__global__ __launch_bounds__(BLK) void chamfer_main_kernel(
    const ushort8* __restrict__ apack8, const ushort8* __restrict__ bpack8,
    float* __restrict__ cand) {
  __shared__ ushort8 blds8[2 * STAGE];    // 16 KB
  const int bd   = blockIdx.x & 7;        // one bd per XCD slot
  const int rest = blockIdx.x >> 3;
  const int ss   = rest & (SSPLIT - 1);
  const int qblk = rest >> 3;
  const int t = threadIdx.x, w = t >> 6, l = t & 63;
  const int acloud = bd, bcloud = bd ^ 1;
  const int qbase = qblk * QPB + w * QPW;

  short8 a0 = __builtin_bit_cast(short8, apack8[(size_t)acloud * NPTS + qbase + (l & 31)]);
  short8 a1 = __builtin_bit_cast(short8, apack8[(size_t)acloud * NPTS + qbase + 32 + (l & 31)]);

  f32x16 m0, m1;
  #pragma unroll
  for (int j = 0; j < 16; ++j) { m0[j] = FLT_MAX; m1[j] = FLT_MAX; }
  const f32x16 zero = {0.f, 0.f, 0.f, 0.f, 0.f, 0.f, 0.f, 0.f,
                       0.f, 0.f, 0.f, 0.f, 0.f, 0.f, 0.f, 0.f};

  const size_t bbase = (size_t)bcloud * 2 * NPTS + (size_t)ss * SRCPB;

  for (int sg = 0; sg < NSTAGE; ++sg) {
    if (sg) __syncthreads();
    #pragma unroll
    for (int i = 0; i < STAGE / BLK; ++i) {   // 2 x (2 x 16B) per thread
      int c = t + BLK * i;
      blds8[c]         = bpack8[bbase + sg * STAGE + c];          // lo plane
      blds8[STAGE + c] = bpack8[bbase + NPTS + sg * STAGE + c];   // hi plane
    }
    __syncthreads();

    const int rb = (l >> 5) * STAGE + (l & 31);
    #pragma unroll 4
    for (int st = 0; st < STAGE / 32; ++st) {   // 16 iters per stage
      short8 bf = __builtin_bit_cast(short8, blds8[rb + st * 32]);
      f32x16 d0 = __builtin_amdgcn_mfma_f32_32x32x16_bf16(a0, bf, zero, 0, 0, 0);
      #pragma unroll
      for (int j = 0; j < 16; ++j) m0[j] = fminf(m0[j], d0[j]);
      f32x16 d1 = __builtin_amdgcn_mfma_f32_32x32x16_bf16(a1, bf, zero, 0, 0, 0);
      #pragma unroll
      for (int j = 0; j < 16; ++j) m1[j] = fminf(m1[j], d1[j]);
    }
  }

  // Min over the 32 source-columns (lanes within each 32-lane group).
  #pragma unroll
  for (int off = 1; off <= 16; off <<= 1) {
    #pragma unroll
    for (int j = 0; j < 16; ++j) {
      m0[j] = fminf(m0[j], __shfl_xor(m0[j], off, 64));
      m1[j] = fminf(m1[j], __shfl_xor(m1[j], off, 64));
    }
  }

  // Lanes 0 and 32 own 16 query-rows each; write per-query partial mins.
  if ((l & 31) == 0) {
    const int radd = (l >> 5) * 4;
    float* cq = cand + ((size_t)(bd * SSPLIT + ss) * NPTS) + qbase;
    #pragma unroll
    for (int r = 0; r < 16; ++r) {
      int row = (r & 3) + 8 * (r >> 2) + radd;
      cq[row]      = m0[r];
      cq[32 + row] = m1[r];
    }
  }
}

// Combine: per query, min over SSPLIT=8 partials + |q|^2, block-sum.
__global__ __launch_bounds__(BLK) void combine_kernel(
    const float* __restrict__ tpl, const float* __restrict__ src,
    const float* __restrict__ cand, float* __restrict__ partial) {
  __shared__ float wsum[BLK / 64];
  const int qblk = blockIdx.x & 31;
  const int bd   = blockIdx.x >> 5;
  const int b = bd >> 1, dir = bd & 1;
  const int t = threadIdx.x;
  const int q = qblk * BLK + t;
  const float* base = cand + (size_t)bd * SSPLIT * NPTS + q;
  float v0 = fminf(base[0 * NPTS], base[1 * NPTS]);
  float v1 = fminf(base[2 * NPTS], base[3 * NPTS]);
  float v2 = fminf(base[4 * NPTS], base[5 * NPTS]);
  float v3 = fminf(base[6 * NPTS], base[7 * NPTS]);
  float v = fminf(fminf(v0, v1), fminf(v2, v3));
  const float* qp = (dir ? src : tpl) + ((size_t)b * NPTS + q) * 3;
  v += fmaf(qp[0], qp[0], fmaf(qp[1], qp[1], qp[2] * qp[2]));
  #pragma unroll
  for (int off = 32; off > 0; off >>= 1) v += __shfl_down(v, off, 64);
  if ((t & 63) == 0) wsum[t >> 6] = v;
  __syncthreads();
  if (t == 0)
    partial[blockIdx.x] = wsum[0] + wsum[1] + wsum[2] + wsum[3];
}

// Final: fixed-order sum of 256 partials; mean over 2*B*N = 32768 mins.
__global__ __launch_bounds__(BLK) void final256_kernel(
    const float* __restrict__ partial, float* __restrict__ out) {
  __shared__ float wsum[BLK / 64];
  int t = threadIdx.x;
  float v = partial[t];
  #pragma unroll
  for (int off = 32; off > 0; off >>= 1) v += __shfl_down(v, off, 64);
  if ((t & 63) == 0) wsum[t >> 6] = v;
  __syncthreads();
  if (t == 0)
    out[0] = (wsum[0] + wsum[1] + wsum[2] + wsum[3]) * (1.0f / 32768.0f);
}

// ---------------- fallback (R2-style) if ws is too small --------------------
#define TILE   2048
#define NTILES (NPTS / TILE)
#define QBLKS  (NPTS / BLK)

__global__ __launch_bounds__(BLK) void chamfer_min_kernel(
    const float* __restrict__ tpl, const float* __restrict__ src,
    float* __restrict__ partial) {
  __shared__ float4 s4[TILE];
  __shared__ float wsum[BLK / 64];
  const int b = blockIdx.z, dir = blockIdx.y;
  const float* qb = (dir == 0 ? tpl : src) + (size_t)b * NPTS * 3;
  const float* rb = (dir == 0 ? src : tpl) + (size_t)b * NPTS * 3;
  const int t = threadIdx.x;
  const int q = blockIdx.x * BLK + t;
  const float qx = qb[3 * q + 0], qy = qb[3 * q + 1], qz = qb[3 * q + 2];
  const float q2 = fmaf(qx, qx, fmaf(qy, qy, qz * qz));
  float b0 = FLT_MAX, b1 = FLT_MAX;
  for (int tile = 0; tile < NTILES; ++tile) {
    const float* rt = rb + 3 * TILE * tile;
    #pragma unroll
    for (int k = 0; k < TILE / BLK; ++k) {
      int p = t + BLK * k;
      float x = rt[3 * p + 0], y = rt[3 * p + 1], z = rt[3 * p + 2];
      s4[p] = make_float4(-2.0f * x, -2.0f * y, -2.0f * z,
                          fmaf(x, x, fmaf(y, y, z * z)));
    }
    __syncthreads();
    #pragma unroll 2
    for (int m = 0; m < TILE; m += 2) {
      float4 p0 = s4[m + 0], p1 = s4[m + 1];
      float d0 = fmaf(qx, p0.x, fmaf(qy, p0.y, fmaf(qz, p0.z, p0.w)));
      float d1 = fmaf(qx, p1.x, fmaf(qy, p1.y, fmaf(qz, p1.z, p1.w)));
      b0 = fminf(b0, fminf(d0, d1));
      b1 = fminf(b1, d0);
    }
    __syncthreads();
  }
  float best = fminf(b0, b1) + q2;
  float v = best;
  #pragma unroll
  for (int off = 32; off > 0; off >>= 1) v += __shfl_down(v, off, 64);
  if ((t & 63) == 0) wsum[t >> 6] = v;
  __syncthreads();
  if (t == 0)
    partial[((b * 2 + dir) * QBLKS) + blockIdx.x] =
        wsum[0] + wsum[1] + wsum[2] + wsum[3];
}

// ----------------------------------------------------------------------------
extern "C" void kernel_launch(void* const* d_in, const int* in_sizes, int n_in,
                              void* d_out, int out_size, void* d_ws, size_t ws_size,
                              hipStream_t stream) {
  const float* tpl = (const float*)d_in[0];   // template (4, 8192, 3) f32
  const float* src = (const float*)d_in[1];   // source   (4, 8192, 3) f32
  float* out = (float*)d_out;

  const size_t a_chunks = (size_t)NBDIR * NPTS;            // 64 K ushort8 (1 MB)
  const size_t b_chunks = (size_t)NBDIR * 2 * NPTS;        // 128 K ushort8 (2 MB)
  const size_t cand_elems = (size_t)NBDIR * SSPLIT * NPTS; // 512 K f32 (2 MB)
  const size_t need = (a_chunks + b_chunks) * 16 +
                      (cand_elems + NBDIR * NQB) * sizeof(float);

  if (ws_size >= need) {
    ushort8* apack8 = (ushort8*)d_ws;
    ushort8* bpack8 = apack8 + a_chunks;
    float*   cand   = (float*)(bpack8 + b_chunks);
    float*   partial = cand + cand_elems;
    prep_kernel<<<(NBDIR * NPTS) / BLK, BLK, 0, stream>>>(tpl, src, apack8, bpack8);
    chamfer_main_kernel<<<NBDIR * SSPLIT * NQB, BLK, 0, stream>>>(apack8, bpack8, cand);
    combine_kernel<<<NBDIR * NQB, BLK, 0, stream>>>(tpl, src, cand, partial);
    final256_kernel<<<1, BLK, 0, stream>>>(partial, out);
  } else {
    float* partial = (float*)d_ws;            // 256 floats
    dim3 grid(QBLKS, 2, NB);
    chamfer_min_kernel<<<grid, BLK, 0, stream>>>(tpl, src, partial);
    final256_kernel<<<1, BLK, 0, stream>>>(partial, out);
  }
}

// Round 13
// 43.870 us; speedup vs baseline: 1.3415x; 1.0406x over previous
//
#include <hip/hip_runtime.h>
#include <float.h>

#define NPTS   8192
#define NB     4
#define BLK    256
#define NBDIR  (NB * 2)             // 8 (batch, direction) pairs
#define SSPLIT 8                    // source splits per bd
#define SRCPB  (NPTS / SSPLIT)      // 1024 sources per block
#define STAGE  512                  // source points per LDS stage (16 KB)
#define NSTAGE (SRCPB / STAGE)      // 2
#define QPW    64                   // queries per wave (2 MFMA tiles of 32)
#define QPB    (4 * QPW)            // 256 queries per block
#define NQB    (NPTS / QPB)         // 32 query blocks per bd

typedef __attribute__((ext_vector_type(8)))  short          short8;
typedef __attribute__((ext_vector_type(8)))  unsigned short ushort8;
typedef __attribute__((ext_vector_type(16))) float          f32x16;

__device__ inline unsigned short f2bf(float x) {           // RNE f32 -> bf16
  unsigned u = __builtin_bit_cast(unsigned, x);
  u = u + 0x7FFFu + ((u >> 16) & 1u);
  return (unsigned short)(u >> 16);
}
__device__ inline float bf2f(unsigned short h) {
  unsigned u = ((unsigned)h) << 16;
  return __builtin_bit_cast(float, u);
}

// Pack per point, K=16 split over two 8-slot halves:
//   A row (both halves identical): [hx,hy,hz,lx,ly,lz,1,0]
//   B lo half: [-2hx,-2hy,-2hz,-2hx,-2hy,-2hz,s2h,0]
//   B hi half: [-2lx,-2ly,-2lz,-2lx,-2ly,-2lz,s2l,0]
// sum_k A[q][k]*B[s][k] = -2*(q.s) + |s|^2, every bf16 product exact in f32.
__global__ __launch_bounds__(BLK) void prep_kernel(
    const float* __restrict__ tpl, const float* __restrict__ src,
    ushort8* __restrict__ apack8, ushort8* __restrict__ bpack8) {
  int p = blockIdx.x * BLK + threadIdx.x;   // 0..65535 = cloud*8192 + i
  int cloud = p >> 13;                      // b*2 + (0=tpl,1=src)
  int i = p & (NPTS - 1);
  int b = cloud >> 1;
  const float* base = ((cloud & 1) ? src : tpl) + ((size_t)b * NPTS + i) * 3;
  float x = base[0], y = base[1], z = base[2];
  unsigned short hx = f2bf(x), hy = f2bf(y), hz = f2bf(z);
  float fx = bf2f(hx), fy = bf2f(hy), fz = bf2f(hz);
  unsigned short lx = f2bf(x - fx), ly = f2bf(y - fy), lz = f2bf(z - fz);
  float s2 = fmaf(x, x, fmaf(y, y, z * z));
  unsigned short s2h = f2bf(s2);
  unsigned short s2l = f2bf(s2 - bf2f(s2h));
  unsigned short nhx = f2bf(-2.0f * fx), nhy = f2bf(-2.0f * fy), nhz = f2bf(-2.0f * fz);
  unsigned short nlx = f2bf(-2.0f * bf2f(lx)), nly = f2bf(-2.0f * bf2f(ly)),
                 nlz = f2bf(-2.0f * bf2f(lz));
  const unsigned short ONE = 0x3F80;

  ushort8 arow = {hx, hy, hz, lx, ly, lz, ONE, 0};
  ushort8 blo  = {nhx, nhy, nhz, nhx, nhy, nhz, s2h, 0};
  ushort8 bhi  = {nlx, nly, nlz, nlx, nly, nlz, s2l, 0};
  apack8[p] = arow;                                      // [cloud][point]
  bpack8[((size_t)cloud * 2 + 0) * NPTS + i] = blo;      // [cloud][half][point]
  bpack8[((size_t)cloud * 2 + 1) * NPTS + i] = bhi;
}

// Main: R12 grid (2048 blocks, 16 KB LDS), but MFMA via inline asm with
// "=&v" VGPR destinations: d0/d1/zero/m all in arch VGPRs -> fmin is pure
// v_min_f32 (no AGPR operand limit, no accvgpr shuttle). MFMA->VALU-read
// hazard covered explicitly by s_nop 7 x2 + s_nop 1 (18 cyc) inside the asm
// block (other waves issue during nops). d1's first read is ~50 cyc after
// issue (16 d0-fmins between).
// Fragment maps: A row=l&31, B col=l&31 (k-half via l>>5, order-invariant
// because A's two k-halves are identical); C/D (verified m74/m101):
// col=l&31, row=(reg&3)+8*(reg>>2)+4*(l>>5).
__global__ __launch_bounds__(BLK) void chamfer_main_kernel(
    const ushort8* __restrict__ apack8, const ushort8* __restrict__ bpack8,
    float* __restrict__ cand) {
  __shared__ ushort8 blds8[2 * STAGE];    // 16 KB
  const int bd   = blockIdx.x & 7;        // one bd per XCD slot
  const int rest = blockIdx.x >> 3;
  const int ss   = rest & (SSPLIT - 1);
  const int qblk = rest >> 3;
  const int t = threadIdx.x, w = t >> 6, l = t & 63;
  const int acloud = bd, bcloud = bd ^ 1;
  const int qbase = qblk * QPB + w * QPW;

  short8 a0 = __builtin_bit_cast(short8, apack8[(size_t)acloud * NPTS + qbase + (l & 31)]);
  short8 a1 = __builtin_bit_cast(short8, apack8[(size_t)acloud * NPTS + qbase + 32 + (l & 31)]);

  f32x16 m0, m1, zero;
  #pragma unroll
  for (int j = 0; j < 16; ++j) { m0[j] = FLT_MAX; m1[j] = FLT_MAX; zero[j] = 0.0f; }

  const size_t bbase = (size_t)bcloud * 2 * NPTS + (size_t)ss * SRCPB;

  for (int sg = 0; sg < NSTAGE; ++sg) {
    if (sg) __syncthreads();
    #pragma unroll
    for (int i = 0; i < STAGE / BLK; ++i) {   // 2 x (2 x 16B) per thread
      int c = t + BLK * i;
      blds8[c]         = bpack8[bbase + sg * STAGE + c];          // lo plane
      blds8[STAGE + c] = bpack8[bbase + NPTS + sg * STAGE + c];   // hi plane
    }
    __syncthreads();

    const int rb = (l >> 5) * STAGE + (l & 31);
    #pragma unroll 2
    for (int st = 0; st < STAGE / 32; ++st) {   // 16 iters per stage
      short8 bf = __builtin_bit_cast(short8, blds8[rb + st * 32]);
      f32x16 d0, d1;
      // Both MFMAs with VGPR dst; 18 cycles of s_nop before the compiler's
      // fmin stream may read d0 (d1's read comes >=32 cyc later).
      asm volatile(
        "v_mfma_f32_32x32x16_bf16 %0, %2, %4, %5\n\t"
        "v_mfma_f32_32x32x16_bf16 %1, %3, %4, %5\n\t"
        "s_nop 7\n\t"
        "s_nop 7\n\t"
        "s_nop 1"
        : "=&v"(d0), "=&v"(d1)
        : "v"(a0), "v"(a1), "v"(bf), "v"(zero));
      #pragma unroll
      for (int j = 0; j < 16; ++j) m0[j] = fminf(m0[j], d0[j]);
      #pragma unroll
      for (int j = 0; j < 16; ++j) m1[j] = fminf(m1[j], d1[j]);
    }
  }

  // Min over the 32 source-columns (lanes within each 32-lane group).
  #pragma unroll
  for (int off = 1; off <= 16; off <<= 1) {
    #pragma unroll
    for (int j = 0; j < 16; ++j) {
      m0[j] = fminf(m0[j], __shfl_xor(m0[j], off, 64));
      m1[j] = fminf(m1[j], __shfl_xor(m1[j], off, 64));
    }
  }

  // Lanes 0 and 32 own 16 query-rows each; write per-query partial mins.
  if ((l & 31) == 0) {
    const int radd = (l >> 5) * 4;
    float* cq = cand + ((size_t)(bd * SSPLIT + ss) * NPTS) + qbase;
    #pragma unroll
    for (int r = 0; r < 16; ++r) {
      int row = (r & 3) + 8 * (r >> 2) + radd;
      cq[row]      = m0[r];
      cq[32 + row] = m1[r];
    }
  }
}

// Combine: per query, min over SSPLIT=8 partials + |q|^2, block-sum.
__global__ __launch_bounds__(BLK) void combine_kernel(
    const float* __restrict__ tpl, const float* __restrict__ src,
    const float* __restrict__ cand, float* __restrict__ partial) {
  __shared__ float wsum[BLK / 64];
  const int qblk = blockIdx.x & 31;
  const int bd   = blockIdx.x >> 5;
  const int b = bd >> 1, dir = bd & 1;
  const int t = threadIdx.x;
  const int q = qblk * BLK + t;
  const float* base = cand + (size_t)bd * SSPLIT * NPTS + q;
  float v0 = fminf(base[0 * NPTS], base[1 * NPTS]);
  float v1 = fminf(base[2 * NPTS], base[3 * NPTS]);
  float v2 = fminf(base[4 * NPTS], base[5 * NPTS]);
  float v3 = fminf(base[6 * NPTS], base[7 * NPTS]);
  float v = fminf(fminf(v0, v1), fminf(v2, v3));
  const float* qp = (dir ? src : tpl) + ((size_t)b * NPTS + q) * 3;
  v += fmaf(qp[0], qp[0], fmaf(qp[1], qp[1], qp[2] * qp[2]));
  #pragma unroll
  for (int off = 32; off > 0; off >>= 1) v += __shfl_down(v, off, 64);
  if ((t & 63) == 0) wsum[t >> 6] = v;
  __syncthreads();
  if (t == 0)
    partial[blockIdx.x] = wsum[0] + wsum[1] + wsum[2] + wsum[3];
}

// Final: fixed-order sum of 256 partials; mean over 2*B*N = 32768 mins.
__global__ __launch_bounds__(BLK) void final256_kernel(
    const float* __restrict__ partial, float* __restrict__ out) {
  __shared__ float wsum[BLK / 64];
  int t = threadIdx.x;
  float v = partial[t];
  #pragma unroll
  for (int off = 32; off > 0; off >>= 1) v += __shfl_down(v, off, 64);
  if ((t & 63) == 0) wsum[t >> 6] = v;
  __syncthreads();
  if (t == 0)
    out[0] = (wsum[0] + wsum[1] + wsum[2] + wsum[3]) * (1.0f / 32768.0f);
}

// ---------------- fallback (R2-style) if ws is too small --------------------
#define TILE   2048
#define NTILES (NPTS / TILE)
#define QBLKS  (NPTS / BLK)

__global__ __launch_bounds__(BLK) void chamfer_min_kernel(
    const float* __restrict__ tpl, const float* __restrict__ src,
    float* __restrict__ partial) {
  __shared__ float4 s4[TILE];
  __shared__ float wsum[BLK / 64];
  const int b = blockIdx.z, dir = blockIdx.y;
  const float* qb = (dir == 0 ? tpl : src) + (size_t)b * NPTS * 3;
  const float* rb = (dir == 0 ? src : tpl) + (size_t)b * NPTS * 3;
  const int t = threadIdx.x;
  const int q = blockIdx.x * BLK + t;
  const float qx = qb[3 * q + 0], qy = qb[3 * q + 1], qz = qb[3 * q + 2];
  const float q2 = fmaf(qx, qx, fmaf(qy, qy, qz * qz));
  float b0 = FLT_MAX, b1 = FLT_MAX;
  for (int tile = 0; tile < NTILES; ++tile) {
    const float* rt = rb + 3 * TILE * tile;
    #pragma unroll
    for (int k = 0; k < TILE / BLK; ++k) {
      int p = t + BLK * k;
      float x = rt[3 * p + 0], y = rt[3 * p + 1], z = rt[3 * p + 2];
      s4[p] = make_float4(-2.0f * x, -2.0f * y, -2.0f * z,
                          fmaf(x, x, fmaf(y, y, z * z)));
    }
    __syncthreads();
    #pragma unroll 2
    for (int m = 0; m < TILE; m += 2) {
      float4 p0 = s4[m + 0], p1 = s4[m + 1];
      float d0 = fmaf(qx, p0.x, fmaf(qy, p0.y, fmaf(qz, p0.z, p0.w)));
      float d1 = fmaf(qx, p1.x, fmaf(qy, p1.y, fmaf(qz, p1.z, p1.w)));
      b0 = fminf(b0, fminf(d0, d1));
      b1 = fminf(b1, d0);
    }
    __syncthreads();
  }
  float best = fminf(b0, b1) + q2;
  float v = best;
  #pragma unroll
  for (int off = 32; off > 0; off >>= 1) v += __shfl_down(v, off, 64);
  if ((t & 63) == 0) wsum[t >> 6] = v;
  __syncthreads();
  if (t == 0)
    partial[((b * 2 + dir) * QBLKS) + blockIdx.x] =
        wsum[0] + wsum[1] + wsum[2] + wsum[3];
}

// ----------------------------------------------------------------------------
extern "C" void kernel_launch(void* const* d_in, const int* in_sizes, int n_in,
                              void* d_out, int out_size, void* d_ws, size_t ws_size,
                              hipStream_t stream) {
  const float* tpl = (const float*)d_in[0];   // template (4, 8192, 3) f32
  const float* src = (const float*)d_in[1];   // source   (4, 8192, 3) f32
  float* out = (float*)d_out;

  const size_t a_chunks = (size_t)NBDIR * NPTS;            // 64 K ushort8 (1 MB)
  const size_t b_chunks = (size_t)NBDIR * 2 * NPTS;        // 128 K ushort8 (2 MB)
  const size_t cand_elems = (size_t)NBDIR * SSPLIT * NPTS; // 512 K f32 (2 MB)
  const size_t need = (a_chunks + b_chunks) * 16 +
                      (cand_elems + NBDIR * NQB) * sizeof(float);

  if (ws_size >= need) {
    ushort8* apack8 = (ushort8*)d_ws;
    ushort8* bpack8 = apack8 + a_chunks;
    float*   cand   = (float*)(bpack8 + b_chunks);
    float*   partial = cand + cand_elems;
    prep_kernel<<<(NBDIR * NPTS) / BLK, BLK, 0, stream>>>(tpl, src, apack8, bpack8);
    chamfer_main_kernel<<<NBDIR * SSPLIT * NQB, BLK, 0, stream>>>(apack8, bpack8, cand);
    combine_kernel<<<NBDIR * NQB, BLK, 0, stream>>>(tpl, src, cand, partial);
    final256_kernel<<<1, BLK, 0, stream>>>(partial, out);
  } else {
    float* partial = (float*)d_ws;            // 256 floats
    dim3 grid(QBLKS, 2, NB);
    chamfer_min_kernel<<<grid, BLK, 0, stream>>>(tpl, src, partial);
    final256_kernel<<<1, BLK, 0, stream>>>(partial, out);
  }
}

// Round 14
// 37.783 us; speedup vs baseline: 1.5576x; 1.1611x over previous
//
#include <hip/hip_runtime.h>
#include <float.h>

#define NPTS   8192
#define NB     4
#define BLK    256
#define NBDIR  (NB * 2)             // 8 (batch, direction) pairs
#define SSPLIT 4                    // source splits per bd
#define SRCPB  (NPTS / SSPLIT)      // 2048 sources per block
#define STAGE  1024                 // source points per LDS stage (32 KB packed)
#define NSTAGE (SRCPB / STAGE)      // 2
#define QPW    64                   // queries per wave (2 MFMA tiles of 32)
#define QPB    (4 * QPW)            // 256 queries per block
#define NQB    (NPTS / QPB)         // 32 query blocks per bd

typedef __attribute__((ext_vector_type(8)))  short          short8;
typedef __attribute__((ext_vector_type(8)))  unsigned short ushort8;
typedef __attribute__((ext_vector_type(16))) float          f32x16;

__device__ inline unsigned short f2bf(float x) {           // RNE f32 -> bf16
  unsigned u = __builtin_bit_cast(unsigned, x);
  u = u + 0x7FFFu + ((u >> 16) & 1u);
  return (unsigned short)(u >> 16);
}
__device__ inline float bf2f(unsigned short h) {
  unsigned u = ((unsigned)h) << 16;
  return __builtin_bit_cast(float, u);
}

// K=16 split packing (identical math to the old prep kernel, now in-kernel):
//   A row (both halves identical): [hx,hy,hz,lx,ly,lz,1,0]
//   B lo half: [-2hx,-2hy,-2hz,-2hx,-2hy,-2hz,s2h,0]
//   B hi half: [-2lx,-2ly,-2lz,-2lx,-2ly,-2lz,s2l,0]
// sum_k A[q][k]*B[s][k] = -2*(q.s) + |s|^2, every bf16 product exact in f32.
__device__ inline ushort8 pack_arow(float x, float y, float z) {
  unsigned short hx = f2bf(x), hy = f2bf(y), hz = f2bf(z);
  unsigned short lx = f2bf(x - bf2f(hx)), ly = f2bf(y - bf2f(hy)),
                 lz = f2bf(z - bf2f(hz));
  ushort8 a = {hx, hy, hz, lx, ly, lz, (unsigned short)0x3F80, 0};
  return a;
}
__device__ inline void pack_brow(float x, float y, float z,
                                 ushort8* blo, ushort8* bhi) {
  unsigned short hx = f2bf(x), hy = f2bf(y), hz = f2bf(z);
  float fx = bf2f(hx), fy = bf2f(hy), fz = bf2f(hz);
  unsigned short lx = f2bf(x - fx), ly = f2bf(y - fy), lz = f2bf(z - fz);
  float s2 = fmaf(x, x, fmaf(y, y, z * z));
  unsigned short s2h = f2bf(s2);
  unsigned short s2l = f2bf(s2 - bf2f(s2h));
  unsigned short nhx = f2bf(-2.0f * fx), nhy = f2bf(-2.0f * fy),
                 nhz = f2bf(-2.0f * fz);
  unsigned short nlx = f2bf(-2.0f * bf2f(lx)), nly = f2bf(-2.0f * bf2f(ly)),
                 nlz = f2bf(-2.0f * bf2f(lz));
  ushort8 lo = {nhx, nhy, nhz, nhx, nhy, nhz, s2h, 0};
  ushort8 hi = {nlx, nly, nlz, nlx, nly, nlz, s2l, 0};
  *blo = lo; *bhi = hi;
}

// Main: R6/R13 measured-best structure with prep FUSED into staging
// (conversion ~112 VALU/thread/stage, noise vs the ~4k-cycle inner phase).
// Inner loop: R13 inline-asm MFMA with "=&v" VGPR dst + s_nop hazard cover;
// consumption is R6's single-d-operand fminf (two-d-operand min3 regressed
// in R7-R9). Grid 1024 = bd(8) x ss(4) x qblk(32), 4 blocks/CU.
// Fragment maps: A row=l&31, B col=l&31 (k-half via l>>5, order-invariant
// because A's two k-halves are identical); C/D (verified m74/m101):
// col=l&31, row=(reg&3)+8*(reg>>2)+4*(l>>5).
__global__ __launch_bounds__(BLK) void chamfer_main_kernel(
    const float* __restrict__ tpl, const float* __restrict__ src,
    float* __restrict__ cand) {
  __shared__ ushort8 blds8[2 * STAGE];    // 32 KB
  const int bd   = blockIdx.x & 7;        // one bd per XCD slot
  const int rest = blockIdx.x >> 3;
  const int ss   = rest & (SSPLIT - 1);
  const int qblk = rest >> 2;
  const int t = threadIdx.x, w = t >> 6, l = t & 63;
  const int b = bd >> 1, dir = bd & 1;
  const int qbase = qblk * QPB + w * QPW;

  const float* qraw = (dir ? src : tpl) + (size_t)b * NPTS * 3;  // queries
  const float* sraw = (dir ? tpl : src) + (size_t)b * NPTS * 3;  // sources

  // A fragments packed in-register (2 query tiles; both k-halves identical).
  short8 a0, a1;
  {
    int q0 = qbase + (l & 31), q1 = qbase + 32 + (l & 31);
    a0 = __builtin_bit_cast(short8,
        pack_arow(qraw[3 * q0], qraw[3 * q0 + 1], qraw[3 * q0 + 2]));
    a1 = __builtin_bit_cast(short8,
        pack_arow(qraw[3 * q1], qraw[3 * q1 + 1], qraw[3 * q1 + 2]));
  }

  f32x16 m0, m1, zero;
  #pragma unroll
  for (int j = 0; j < 16; ++j) { m0[j] = FLT_MAX; m1[j] = FLT_MAX; zero[j] = 0.0f; }

  const int sbase = ss * SRCPB;

  for (int sg = 0; sg < NSTAGE; ++sg) {
    if (sg) __syncthreads();
    // Stage 1024 source points with fused f32 -> split-bf16 packing.
    #pragma unroll
    for (int i = 0; i < STAGE / BLK; ++i) {
      int idx = t + BLK * i;
      int p = sbase + sg * STAGE + idx;
      ushort8 blo, bhi;
      pack_brow(sraw[3 * p], sraw[3 * p + 1], sraw[3 * p + 2], &blo, &bhi);
      blds8[idx]         = blo;           // lo plane
      blds8[STAGE + idx] = bhi;           // hi plane
    }
    __syncthreads();

    const int rb = (l >> 5) * STAGE + (l & 31);
    #pragma unroll 2
    for (int st = 0; st < STAGE / 32; ++st) {   // 32 iters per stage
      short8 bf = __builtin_bit_cast(short8, blds8[rb + st * 32]);
      f32x16 d0, d1;
      asm volatile(
        "v_mfma_f32_32x32x16_bf16 %0, %2, %4, %5\n\t"
        "v_mfma_f32_32x32x16_bf16 %1, %3, %4, %5\n\t"
        "s_nop 7\n\t"
        "s_nop 7\n\t"
        "s_nop 1"
        : "=&v"(d0), "=&v"(d1)
        : "v"(a0), "v"(a1), "v"(bf), "v"(zero));
      #pragma unroll
      for (int j = 0; j < 16; ++j) m0[j] = fminf(m0[j], d0[j]);
      #pragma unroll
      for (int j = 0; j < 16; ++j) m1[j] = fminf(m1[j], d1[j]);
    }
  }

  // Min over the 32 source-columns (lanes within each 32-lane group).
  #pragma unroll
  for (int off = 1; off <= 16; off <<= 1) {
    #pragma unroll
    for (int j = 0; j < 16; ++j) {
      m0[j] = fminf(m0[j], __shfl_xor(m0[j], off, 64));
      m1[j] = fminf(m1[j], __shfl_xor(m1[j], off, 64));
    }
  }

  // Lanes 0 and 32 own 16 query-rows each (compile-time indices only).
  if ((l & 31) == 0) {
    const int radd = (l >> 5) * 4;
    float* cq = cand + ((size_t)(bd * SSPLIT + ss) * NPTS) + qbase;
    #pragma unroll
    for (int r = 0; r < 16; ++r) {
      int row = (r & 3) + 8 * (r >> 2) + radd;
      cq[row]      = m0[r];
      cq[32 + row] = m1[r];
    }
  }
}

// Combine: per query, min over SSPLIT=4 partials + |q|^2, block-sum.
__global__ __launch_bounds__(BLK) void combine_kernel(
    const float* __restrict__ tpl, const float* __restrict__ src,
    const float* __restrict__ cand, float* __restrict__ partial) {
  __shared__ float wsum[BLK / 64];
  const int qblk = blockIdx.x & 31;
  const int bd   = blockIdx.x >> 5;
  const int b = bd >> 1, dir = bd & 1;
  const int t = threadIdx.x;
  const int q = qblk * BLK + t;
  const float* base = cand + (size_t)bd * SSPLIT * NPTS + q;
  float v = fminf(fminf(base[0 * NPTS], base[1 * NPTS]),
                  fminf(base[2 * NPTS], base[3 * NPTS]));
  const float* qp = (dir ? src : tpl) + ((size_t)b * NPTS + q) * 3;
  v += fmaf(qp[0], qp[0], fmaf(qp[1], qp[1], qp[2] * qp[2]));
  #pragma unroll
  for (int off = 32; off > 0; off >>= 1) v += __shfl_down(v, off, 64);
  if ((t & 63) == 0) wsum[t >> 6] = v;
  __syncthreads();
  if (t == 0)
    partial[blockIdx.x] = wsum[0] + wsum[1] + wsum[2] + wsum[3];
}

// Final: fixed-order sum of 256 partials; mean over 2*B*N = 32768 mins.
__global__ __launch_bounds__(BLK) void final256_kernel(
    const float* __restrict__ partial, float* __restrict__ out) {
  __shared__ float wsum[BLK / 64];
  int t = threadIdx.x;
  float v = partial[t];
  #pragma unroll
  for (int off = 32; off > 0; off >>= 1) v += __shfl_down(v, off, 64);
  if ((t & 63) == 0) wsum[t >> 6] = v;
  __syncthreads();
  if (t == 0)
    out[0] = (wsum[0] + wsum[1] + wsum[2] + wsum[3]) * (1.0f / 32768.0f);
}

// ---------------- fallback (R2-style) if ws is too small --------------------
#define TILE   2048
#define NTILES (NPTS / TILE)
#define QBLKS  (NPTS / BLK)

__global__ __launch_bounds__(BLK) void chamfer_min_kernel(
    const float* __restrict__ tpl, const float* __restrict__ src,
    float* __restrict__ partial) {
  __shared__ float4 s4[TILE];
  __shared__ float wsum[BLK / 64];
  const int b = blockIdx.z, dir = blockIdx.y;
  const float* qb = (dir == 0 ? tpl : src) + (size_t)b * NPTS * 3;
  const float* rb = (dir == 0 ? src : tpl) + (size_t)b * NPTS * 3;
  const int t = threadIdx.x;
  const int q = blockIdx.x * BLK + t;
  const float qx = qb[3 * q + 0], qy = qb[3 * q + 1], qz = qb[3 * q + 2];
  const float q2 = fmaf(qx, qx, fmaf(qy, qy, qz * qz));
  float b0 = FLT_MAX, b1 = FLT_MAX;
  for (int tile = 0; tile < NTILES; ++tile) {
    const float* rt = rb + 3 * TILE * tile;
    #pragma unroll
    for (int k = 0; k < TILE / BLK; ++k) {
      int p = t + BLK * k;
      float x = rt[3 * p + 0], y = rt[3 * p + 1], z = rt[3 * p + 2];
      s4[p] = make_float4(-2.0f * x, -2.0f * y, -2.0f * z,
                          fmaf(x, x, fmaf(y, y, z * z)));
    }
    __syncthreads();
    #pragma unroll 2
    for (int m = 0; m < TILE; m += 2) {
      float4 p0 = s4[m + 0], p1 = s4[m + 1];
      float d0 = fmaf(qx, p0.x, fmaf(qy, p0.y, fmaf(qz, p0.z, p0.w)));
      float d1 = fmaf(qx, p1.x, fmaf(qy, p1.y, fmaf(qz, p1.z, p1.w)));
      b0 = fminf(b0, fminf(d0, d1));
      b1 = fminf(b1, d0);
    }
    __syncthreads();
  }
  float best = fminf(b0, b1) + q2;
  float v = best;
  #pragma unroll
  for (int off = 32; off > 0; off >>= 1) v += __shfl_down(v, off, 64);
  if ((t & 63) == 0) wsum[t >> 6] = v;
  __syncthreads();
  if (t == 0)
    partial[((b * 2 + dir) * QBLKS) + blockIdx.x] =
        wsum[0] + wsum[1] + wsum[2] + wsum[3];
}

// ----------------------------------------------------------------------------
extern "C" void kernel_launch(void* const* d_in, const int* in_sizes, int n_in,
                              void* d_out, int out_size, void* d_ws, size_t ws_size,
                              hipStream_t stream) {
  const float* tpl = (const float*)d_in[0];   // template (4, 8192, 3) f32
  const float* src = (const float*)d_in[1];   // source   (4, 8192, 3) f32
  float* out = (float*)d_out;

  const size_t cand_elems = (size_t)NBDIR * SSPLIT * NPTS;   // 256 K f32 (1 MB)
  const size_t need = (cand_elems + NBDIR * NQB) * sizeof(float);

  if (ws_size >= need) {
    float* cand    = (float*)d_ws;
    float* partial = cand + cand_elems;
    chamfer_main_kernel<<<NBDIR * SSPLIT * NQB, BLK, 0, stream>>>(tpl, src, cand);
    combine_kernel<<<NBDIR * NQB, BLK, 0, stream>>>(tpl, src, cand, partial);
    final256_kernel<<<1, BLK, 0, stream>>>(partial, out);
  } else {
    float* partial = (float*)d_ws;            // 256 floats
    dim3 grid(QBLKS, 2, NB);
    chamfer_min_kernel<<<grid, BLK, 0, stream>>>(tpl, src, partial);
    final256_kernel<<<1, BLK, 0, stream>>>(partial, out);
  }
}

// Round 15
// 30.158 us; speedup vs baseline: 1.9514x; 1.2528x over previous
//
#include <hip/hip_runtime.h>
#include <float.h>

#define NPTS   8192
#define NB     4
#define NBDIR  (NB * 2)             // 8 (batch, direction) pairs
#define BLKF   512                  // fused kernel: 8 waves
#define QPW    32                   // one 32-query MFMA tile per wave
#define QPB    (8 * QPW)            // 256 queries per block
#define NQB    (NPTS / QPB)         // 32 query blocks per bd
#define STAGE  1024                 // source points per LDS stage (32 KB packed)
#define NSTAGE (NPTS / STAGE)       // 8 stages: block sweeps ALL sources
#define BLK    256                  // final/fallback block

typedef __attribute__((ext_vector_type(8)))  short          short8;
typedef __attribute__((ext_vector_type(8)))  unsigned short ushort8;
typedef __attribute__((ext_vector_type(16))) float          f32x16;

__device__ inline unsigned short f2bf(float x) {           // RNE f32 -> bf16
  unsigned u = __builtin_bit_cast(unsigned, x);
  u = u + 0x7FFFu + ((u >> 16) & 1u);
  return (unsigned short)(u >> 16);
}
__device__ inline float bf2f(unsigned short h) {
  unsigned u = ((unsigned)h) << 16;
  return __builtin_bit_cast(float, u);
}

// K=16 split packing:
//   A row (both halves identical): [hx,hy,hz,lx,ly,lz,1,0]
//   B lo half: [-2hx,-2hy,-2hz,-2hx,-2hy,-2hz,s2h,0]
//   B hi half: [-2lx,-2ly,-2lz,-2lx,-2ly,-2lz,s2l,0]
// sum_k A[q][k]*B[s][k] = -2*(q.s) + |s|^2, every bf16 product exact in f32.
__device__ inline ushort8 pack_arow(float x, float y, float z) {
  unsigned short hx = f2bf(x), hy = f2bf(y), hz = f2bf(z);
  unsigned short lx = f2bf(x - bf2f(hx)), ly = f2bf(y - bf2f(hy)),
                 lz = f2bf(z - bf2f(hz));
  ushort8 a = {hx, hy, hz, lx, ly, lz, (unsigned short)0x3F80, 0};
  return a;
}
__device__ inline void pack_brow(float x, float y, float z,
                                 ushort8* blo, ushort8* bhi) {
  unsigned short hx = f2bf(x), hy = f2bf(y), hz = f2bf(z);
  float fx = bf2f(hx), fy = bf2f(hy), fz = bf2f(hz);
  unsigned short lx = f2bf(x - fx), ly = f2bf(y - fy), lz = f2bf(z - fz);
  float s2 = fmaf(x, x, fmaf(y, y, z * z));
  unsigned short s2h = f2bf(s2);
  unsigned short s2l = f2bf(s2 - bf2f(s2h));
  unsigned short nhx = f2bf(-2.0f * fx), nhy = f2bf(-2.0f * fy),
                 nhz = f2bf(-2.0f * fz);
  unsigned short nlx = f2bf(-2.0f * bf2f(lx)), nly = f2bf(-2.0f * bf2f(ly)),
                 nlz = f2bf(-2.0f * bf2f(lz));
  ushort8 lo = {nhx, nhy, nhz, nhx, nhy, nhz, s2h, 0};
  ushort8 hi = {nlx, nly, nlz, nlx, nly, nlz, s2l, 0};
  *blo = lo; *bhi = hi;
}

// Fused main: query-only grid split -> per-query min completes IN-BLOCK, so
// cand + combine disappear (R14's remaining pipeline fat). 256 blocks of 512
// threads (8 waves x 32 queries), each sweeps all 8192 sources in 8 staged
// LDS chunks. Per iter: 1 ds_read_b128 + 1 MFMA + 16 fminf (R6 consumption:
// single-d-operand fmin; two-d-operand min3 regressed in R7-R9).
// Epilogue: xor-reduce over 32 source-columns, +|q|^2, block-sum -> 1 float.
// Fragment maps: A row=l&31, B col=l&31 (k-half via l>>5, order-invariant
// because A's two k-halves are identical); C/D (verified m74/m101):
// col=l&31, row=(reg&3)+8*(reg>>2)+4*(l>>5).
__global__ __launch_bounds__(BLKF) void chamfer_fused_kernel(
    const float* __restrict__ tpl, const float* __restrict__ src,
    float* __restrict__ partial) {
  __shared__ ushort8 blds8[2 * STAGE];    // 32 KB
  __shared__ float red[16];
  const int bd   = blockIdx.x & 7;        // one bd per XCD slot
  const int qblk = blockIdx.x >> 3;
  const int t = threadIdx.x, w = t >> 6, l = t & 63;
  const int b = bd >> 1, dir = bd & 1;
  const int qbase = qblk * QPB + w * QPW;

  const float* qraw = (dir ? src : tpl) + (size_t)b * NPTS * 3;  // queries
  const float* sraw = (dir ? tpl : src) + (size_t)b * NPTS * 3;  // sources

  // A fragment packed in-register (one 32-query tile per wave).
  short8 a0;
  {
    int q0 = qbase + (l & 31);
    a0 = __builtin_bit_cast(short8,
        pack_arow(qraw[3 * q0], qraw[3 * q0 + 1], qraw[3 * q0 + 2]));
  }

  f32x16 m0;
  #pragma unroll
  for (int j = 0; j < 16; ++j) m0[j] = FLT_MAX;
  const f32x16 zero = {0.f, 0.f, 0.f, 0.f, 0.f, 0.f, 0.f, 0.f,
                       0.f, 0.f, 0.f, 0.f, 0.f, 0.f, 0.f, 0.f};

  for (int sg = 0; sg < NSTAGE; ++sg) {
    if (sg) __syncthreads();
    // Stage 1024 source points with fused f32 -> split-bf16 packing.
    #pragma unroll
    for (int i = 0; i < STAGE / BLKF; ++i) {  // 2 pts per thread
      int idx = t + BLKF * i;
      int p = sg * STAGE + idx;
      ushort8 blo, bhi;
      pack_brow(sraw[3 * p], sraw[3 * p + 1], sraw[3 * p + 2], &blo, &bhi);
      blds8[idx]         = blo;           // lo plane
      blds8[STAGE + idx] = bhi;           // hi plane
    }
    __syncthreads();

    const int rb = (l >> 5) * STAGE + (l & 31);
    #pragma unroll 4
    for (int st = 0; st < STAGE / 32; ++st) {   // 32 iters per stage
      short8 bf = __builtin_bit_cast(short8, blds8[rb + st * 32]);
      f32x16 d0 = __builtin_amdgcn_mfma_f32_32x32x16_bf16(a0, bf, zero, 0, 0, 0);
      #pragma unroll
      for (int j = 0; j < 16; ++j) m0[j] = fminf(m0[j], d0[j]);
    }
  }

  // Min over the 32 source-columns (lanes within each 32-lane group).
  #pragma unroll
  for (int off = 1; off <= 16; off <<= 1) {
    #pragma unroll
    for (int j = 0; j < 16; ++j)
      m0[j] = fminf(m0[j], __shfl_xor(m0[j], off, 64));
  }

  // Lanes 0 and 32 hold 16 query-rows each; add |q|^2 and sum (per-lane).
  float lsum = 0.0f;
  if ((l & 31) == 0) {
    const int radd = (l >> 5) * 4;
    #pragma unroll
    for (int r = 0; r < 16; ++r) {
      int row = (r & 3) + 8 * (r >> 2) + radd;
      int q = qbase + row;
      float x = qraw[3 * q], y = qraw[3 * q + 1], z = qraw[3 * q + 2];
      lsum += m0[r] + fmaf(x, x, fmaf(y, y, z * z));
    }
    red[w * 2 + (l >> 5)] = lsum;
  }
  __syncthreads();
  if (t == 0) {
    float s = 0.0f;
    #pragma unroll
    for (int i = 0; i < 16; ++i) s += red[i];
    partial[blockIdx.x] = s;
  }
}

// Final: fixed-order sum of 256 partials; mean over 2*B*N = 32768 mins.
__global__ __launch_bounds__(BLK) void final256_kernel(
    const float* __restrict__ partial, float* __restrict__ out) {
  __shared__ float wsum[BLK / 64];
  int t = threadIdx.x;
  float v = partial[t];
  #pragma unroll
  for (int off = 32; off > 0; off >>= 1) v += __shfl_down(v, off, 64);
  if ((t & 63) == 0) wsum[t >> 6] = v;
  __syncthreads();
  if (t == 0)
    out[0] = (wsum[0] + wsum[1] + wsum[2] + wsum[3]) * (1.0f / 32768.0f);
}

// ---------------- fallback (R2-style) if ws is too small --------------------
#define TILE   2048
#define NTILES (NPTS / TILE)
#define QBLKS  (NPTS / BLK)

__global__ __launch_bounds__(BLK) void chamfer_min_kernel(
    const float* __restrict__ tpl, const float* __restrict__ src,
    float* __restrict__ partial) {
  __shared__ float4 s4[TILE];
  __shared__ float wsum[BLK / 64];
  const int b = blockIdx.z, dir = blockIdx.y;
  const float* qb = (dir == 0 ? tpl : src) + (size_t)b * NPTS * 3;
  const float* rb = (dir == 0 ? src : tpl) + (size_t)b * NPTS * 3;
  const int t = threadIdx.x;
  const int q = blockIdx.x * BLK + t;
  const float qx = qb[3 * q + 0], qy = qb[3 * q + 1], qz = qb[3 * q + 2];
  const float q2 = fmaf(qx, qx, fmaf(qy, qy, qz * qz));
  float b0 = FLT_MAX, b1 = FLT_MAX;
  for (int tile = 0; tile < NTILES; ++tile) {
    const float* rt = rb + 3 * TILE * tile;
    #pragma unroll
    for (int k = 0; k < TILE / BLK; ++k) {
      int p = t + BLK * k;
      float x = rt[3 * p + 0], y = rt[3 * p + 1], z = rt[3 * p + 2];
      s4[p] = make_float4(-2.0f * x, -2.0f * y, -2.0f * z,
                          fmaf(x, x, fmaf(y, y, z * z)));
    }
    __syncthreads();
    #pragma unroll 2
    for (int m = 0; m < TILE; m += 2) {
      float4 p0 = s4[m + 0], p1 = s4[m + 1];
      float d0 = fmaf(qx, p0.x, fmaf(qy, p0.y, fmaf(qz, p0.z, p0.w)));
      float d1 = fmaf(qx, p1.x, fmaf(qy, p1.y, fmaf(qz, p1.z, p1.w)));
      b0 = fminf(b0, fminf(d0, d1));
      b1 = fminf(b1, d0);
    }
    __syncthreads();
  }
  float best = fminf(b0, b1) + q2;
  float v = best;
  #pragma unroll
  for (int off = 32; off > 0; off >>= 1) v += __shfl_down(v, off, 64);
  if ((t & 63) == 0) wsum[t >> 6] = v;
  __syncthreads();
  if (t == 0)
    partial[((b * 2 + dir) * QBLKS) + blockIdx.x] =
        wsum[0] + wsum[1] + wsum[2] + wsum[3];
}

// ----------------------------------------------------------------------------
extern "C" void kernel_launch(void* const* d_in, const int* in_sizes, int n_in,
                              void* d_out, int out_size, void* d_ws, size_t ws_size,
                              hipStream_t stream) {
  const float* tpl = (const float*)d_in[0];   // template (4, 8192, 3) f32
  const float* src = (const float*)d_in[1];   // source   (4, 8192, 3) f32
  float* out = (float*)d_out;
  float* partial = (float*)d_ws;              // 256 floats

  if (ws_size >= 256 * sizeof(float)) {
    chamfer_fused_kernel<<<NBDIR * NQB, BLKF, 0, stream>>>(tpl, src, partial);
    final256_kernel<<<1, BLK, 0, stream>>>(partial, out);
  } else {
    dim3 grid(QBLKS, 2, NB);
    chamfer_min_kernel<<<grid, BLK, 0, stream>>>(tpl, src, partial);
    final256_kernel<<<1, BLK, 0, stream>>>(partial, out);
  }
}